// Round 8
// baseline (340.579 us; speedup 1.0000x reference)
//
#include <hip/hip_runtime.h>
#include <cstdint>

#define D_EDGES 64
#define K_KEEP  32

// Bit-exact replication of numpy's SIMD f32 exp (Cephes-based, max ULP 2.52).
// Verified: absmax 0 vs the np reference (rounds 3-7).
__device__ __forceinline__ float np_expf(float x) {
    const float log2e     = 1.44269504088896341f;
    const float cvt_magic = 12582912.0f;            // 1.5 * 2^23 RNE trick
    const float neg_ln2hi = -0.693359375f;
    const float neg_ln2lo = 2.12194440e-4f;
    const float p0 = 1.9875691500E-4f;
    const float p1 = 1.3981999507E-3f;
    const float p2 = 8.3334519073E-3f;
    const float p3 = 4.1665795894E-2f;
    const float p4 = 1.6666665459E-1f;
    const float p5 = 5.0000001201E-1f;

    float q = fmaf(x, log2e, cvt_magic);
    q -= cvt_magic;
    x = fmaf(q, neg_ln2hi, x);
    x = fmaf(q, neg_ln2lo, x);
    float x2 = x * x;
    float poly = fmaf(p0, x, p1);
    poly = fmaf(poly, x, p2);
    poly = fmaf(poly, x, p3);
    poly = fmaf(poly, x, p4);
    poly = fmaf(poly, x, p5);
    poly = fmaf(poly, x2, x);
    poly = poly + 1.0f;
    return ldexpf(poly, (int)q);
}

__device__ __forceinline__ float sigmoid_np(float x) {
    float e = np_expf(-x);
    return 1.0f / (1.0f + e);
}

__global__ void sigmoid_kernel(const float* __restrict__ logits,
                               float* __restrict__ s, int n) {
    int i = blockIdx.x * blockDim.x + threadIdx.x;
    if (i < n) s[i] = sigmoid_np(logits[i]);
}

// ---------------- 32-bit fast-path shuffle helpers (verified R6/R7) ----------------
template <int CTRL>
__device__ __forceinline__ unsigned xor_dpp_u32(unsigned v) {
    return (unsigned)__builtin_amdgcn_update_dpp((int)v, (int)v, CTRL, 0xF, 0xF, true);
}

template <int J>
__device__ __forceinline__ unsigned xorshfl_u32(unsigned v, int addr32) {
    if constexpr (J == 1)       return xor_dpp_u32<0xB1>(v);    // quad_perm [1,0,3,2]
    else if constexpr (J == 2)  return xor_dpp_u32<0x4E>(v);    // quad_perm [2,3,0,1]
    else if constexpr (J == 4)  return (unsigned)__builtin_amdgcn_ds_swizzle((int)v, 0x101F);
    else if constexpr (J == 8)  return xor_dpp_u32<0x128>(v);   // row_ror:8 == xor8
    else if constexpr (J == 16) return (unsigned)__builtin_amdgcn_ds_swizzle((int)v, 0x401F);
    else                        return (unsigned)__builtin_amdgcn_ds_bpermute(addr32, (int)v);
}

// Dual compare-exchange: two independent sort chains (2 segments/wave, ILP=2).
template <int J>
__device__ __forceinline__ void stage32x2(unsigned& ka, unsigned& kb,
                                          bool dir, int addr32) {
    unsigned oa = xorshfl_u32<J>(ka, addr32);
    unsigned ob = xorshfl_u32<J>(kb, addr32);
    unsigned mxa = (ka > oa) ? ka : oa;
    unsigned mna = (ka > oa) ? oa : ka;
    unsigned mxb = (kb > ob) ? kb : ob;
    unsigned mnb = (kb > ob) ? ob : kb;
    ka = dir ? mxa : mna;
    kb = dir ? mxb : mnb;
}

// ---------------- u64 slow-path (verified rounds 3-7) ----------------
template <int CTRL>
__device__ __forceinline__ unsigned long long xor_dpp_u64(unsigned long long v) {
    int lo = (int)(unsigned)v;
    int hi = (int)(v >> 32);
    lo = __builtin_amdgcn_update_dpp(lo, lo, CTRL, 0xF, 0xF, true);
    hi = __builtin_amdgcn_update_dpp(hi, hi, CTRL, 0xF, 0xF, true);
    return ((unsigned long long)(unsigned)hi << 32) | (unsigned)lo;
}

template <int OFF>
__device__ __forceinline__ unsigned long long xor_swz_u64(unsigned long long v) {
    int lo = (int)(unsigned)v;
    int hi = (int)(v >> 32);
    lo = __builtin_amdgcn_ds_swizzle(lo, OFF);
    hi = __builtin_amdgcn_ds_swizzle(hi, OFF);
    return ((unsigned long long)(unsigned)hi << 32) | (unsigned)lo;
}

template <int J>
__device__ __forceinline__ unsigned long long xorshfl_u64(unsigned long long v) {
    if constexpr (J == 1)       return xor_dpp_u64<0xB1>(v);
    else if constexpr (J == 2)  return xor_dpp_u64<0x4E>(v);
    else if constexpr (J == 4)  return xor_swz_u64<0x101F>(v);
    else if constexpr (J == 8)  return xor_dpp_u64<0x128>(v);
    else if constexpr (J == 16) return xor_swz_u64<0x401F>(v);
    else {
        int lo = (int)(unsigned)v;
        int hi = (int)(v >> 32);
        lo = __shfl_xor(lo, 32, 64);
        hi = __shfl_xor(hi, 32, 64);
        return ((unsigned long long)(unsigned)hi << 32) | (unsigned)lo;
    }
}

template <int K, int J>
__device__ __forceinline__ void stage64(unsigned long long& key, int lane) {
    unsigned long long other = xorshfl_u64<J>(key);
    const bool dir = ((lane & J) == 0) == ((lane & K) == 0);
    key = ((key > other) != dir) ? other : key;
}

// Full verified u64 sort; returns origLane of this lane's rank.
__device__ __noinline__ int sort64_slow(float sim, int lane) {
    unsigned long long key =
        ((unsigned long long)__float_as_uint(sim) << 6) |
        (unsigned long long)(lane ^ 63);
    stage64<2, 1>(key, lane);
    stage64<4, 2>(key, lane);   stage64<4, 1>(key, lane);
    stage64<8, 4>(key, lane);   stage64<8, 2>(key, lane);   stage64<8, 1>(key, lane);
    stage64<16, 8>(key, lane);  stage64<16, 4>(key, lane);  stage64<16, 2>(key, lane);
    stage64<16, 1>(key, lane);
    stage64<32, 16>(key, lane); stage64<32, 8>(key, lane);  stage64<32, 4>(key, lane);
    stage64<32, 2>(key, lane);  stage64<32, 1>(key, lane);
    stage64<64, 32>(key, lane); stage64<64, 16>(key, lane); stage64<64, 8>(key, lane);
    stage64<64, 4>(key, lane);  stage64<64, 2>(key, lane);  stage64<64, 1>(key, lane);
    return ((int)(key & 63)) ^ 63;
}

// Two segments (128 edges) per wave. Identical to R7 except: all divergent /
// streaming global accesses are NON-TEMPORAL (no L1 allocation) to test the
// L1-fill-bound hypothesis for the ~130us plateau.
__global__ __launch_bounds__(256)
void topk_kernel(const int* __restrict__ edge_index,   // [2, E]
                 const float* __restrict__ stab,       // sigmoid table [N]
                 int* __restrict__ out,                // [2, nseg*K]
                 int E, int nseg, int outHalf) {
    const int tid = threadIdx.x;
    const int lane = tid & 63;
    const int wp = (blockIdx.x << 2) | (tid >> 6);   // wave-pair id, 4 waves/blk
    const int segA = wp << 1;
    if (segA >= nseg) return;
    const int segB = segA + 1;
    const bool hasB = segB < nseg;

    const int baseA = segA << 6;                      // edge offset of seg A
    // Streaming, zero-reuse: NT load (no L1 allocate).
    int srcA = __builtin_nontemporal_load(edge_index + baseA + lane);
    int srcB = hasB ? __builtin_nontemporal_load(edge_index + baseA + 64 + lane) : 0;

    // Segment-uniform dst via the scalar path.
    int sbase = __builtin_amdgcn_readfirstlane(baseA);
    int dstA = edge_index[E + sbase];
    int dstB = hasB ? edge_index[E + sbase + 64] : dstA;

    float sdA = stab[dstA];                           // uniform (s_load)
    float sdB = stab[dstB];
    // The divergent gather — NT: bypass L1 allocate, serve from L2.
    float ssA = __builtin_nontemporal_load(stab + srcA);
    float ssB = __builtin_nontemporal_load(stab + srcB);
    float simA = 1.0f - fabsf(ssA - sdA);             // np f32 pipeline
    float simB = hasB ? (1.0f - fabsf(ssB - sdB)) : 1.0f;

    // Hoisted lane-bit predicates (lane masks in SGPR pairs).
    const bool b1  = (lane & 1)  == 0;
    const bool b2  = (lane & 2)  == 0;
    const bool b4  = (lane & 4)  == 0;
    const bool b8  = (lane & 8)  == 0;
    const bool b16 = (lane & 16) == 0;
    const bool b32 = (lane & 32) == 0;
    const int addr32 = (lane ^ 32) << 2;              // bpermute addr for j=32

    int origA, origB;
    // Fast path: all sims in [0.0625, 1] -> lossless 32-bit key
    // ((bits(sim)-0x3D800000)<<6)|(lane^63), order-isomorphic to the u64 key.
    if (__all(fminf(simA, simB) >= 0.0625f)) {
        unsigned ka = ((__float_as_uint(simA) - 0x3D800000u) << 6) | (unsigned)(lane ^ 63);
        unsigned kb = ((__float_as_uint(simB) - 0x3D800000u) << 6) | (unsigned)(lane ^ 63);

        stage32x2<1>(ka, kb, b1 == b2, addr32);
        stage32x2<2>(ka, kb, b2 == b4, addr32);  stage32x2<1>(ka, kb, b1 == b4, addr32);
        stage32x2<4>(ka, kb, b4 == b8, addr32);  stage32x2<2>(ka, kb, b2 == b8, addr32);
        stage32x2<1>(ka, kb, b1 == b8, addr32);
        stage32x2<8>(ka, kb, b8 == b16, addr32); stage32x2<4>(ka, kb, b4 == b16, addr32);
        stage32x2<2>(ka, kb, b2 == b16, addr32); stage32x2<1>(ka, kb, b1 == b16, addr32);
        stage32x2<16>(ka, kb, b16 == b32, addr32); stage32x2<8>(ka, kb, b8 == b32, addr32);
        stage32x2<4>(ka, kb, b4 == b32, addr32);   stage32x2<2>(ka, kb, b2 == b32, addr32);
        stage32x2<1>(ka, kb, b1 == b32, addr32);
        stage32x2<32>(ka, kb, b32, addr32); stage32x2<16>(ka, kb, b16, addr32);
        stage32x2<8>(ka, kb, b8, addr32);   stage32x2<4>(ka, kb, b4, addr32);
        stage32x2<2>(ka, kb, b2, addr32);   stage32x2<1>(ka, kb, b1, addr32);

        origA = ((int)ka & 63) ^ 63;
        origB = ((int)kb & 63) ^ 63;
    } else {
        origA = sort64_slow(simA, lane);
        origB = sort64_slow(simB, lane);
    }

    // Lane r (r<32) holds rank-r origin; pull the owning lane's src.
    int selA = __builtin_amdgcn_ds_bpermute(origA << 2, srcA);
    int selB = __builtin_amdgcn_ds_bpermute(origB << 2, srcB);

    // Row 0: selected src, ranks 0..31 per segment (NT stores, write-once).
    if (lane < K_KEEP) {
        int base = (segA << 5) | lane;
        __builtin_nontemporal_store(selA, out + base);
        if (hasB) __builtin_nontemporal_store(selB, out + base + K_KEEP);
    }
    // Row 1: dst (segment-constant), coalesced across both segments.
    if (lane < K_KEEP || hasB) {
        int dstv = (lane < K_KEEP) ? dstA : dstB;
        __builtin_nontemporal_store(dstv, out + outHalf + (segA << 5) + lane);
    }
}

extern "C" void kernel_launch(void* const* d_in, const int* in_sizes, int n_in,
                              void* d_out, int out_size, void* d_ws, size_t ws_size,
                              hipStream_t stream) {
    const float* logits = (const float*)d_in[0];
    const int* edge_index = (const int*)d_in[1];
    int N = in_sizes[0];
    int E = in_sizes[1] / 2;             // 2^24, fits int
    int nseg = E / D_EDGES;              // 2^18
    int outHalf = nseg * K_KEEP;         // 2^23
    int* out = (int*)d_out;

    float* stab = (float*)d_ws;          // 1 MB sigmoid table
    sigmoid_kernel<<<(N + 255) / 256, 256, 0, stream>>>(logits, stab, N);

    int npairs = (nseg + 1) / 2;         // 2 segments per wave
    int blocks = (npairs + 3) / 4;       // 4 waves per 256-thread block
    topk_kernel<<<blocks, 256, 0, stream>>>(edge_index, stab, out,
                                            E, nseg, outHalf);
}

// Round 9
// 284.288 us; speedup vs baseline: 1.1980x; 1.1980x over previous
//
#include <hip/hip_runtime.h>
#include <cstdint>

#define D_EDGES 64
#define K_KEEP  32

// Bit-exact replication of numpy's SIMD f32 exp (Cephes-based, max ULP 2.52).
// Verified: absmax 0 vs the np reference (rounds 3-8).
__device__ __forceinline__ float np_expf(float x) {
    const float log2e     = 1.44269504088896341f;
    const float cvt_magic = 12582912.0f;            // 1.5 * 2^23 RNE trick
    const float neg_ln2hi = -0.693359375f;
    const float neg_ln2lo = 2.12194440e-4f;
    const float p0 = 1.9875691500E-4f;
    const float p1 = 1.3981999507E-3f;
    const float p2 = 8.3334519073E-3f;
    const float p3 = 4.1665795894E-2f;
    const float p4 = 1.6666665459E-1f;
    const float p5 = 5.0000001201E-1f;

    float q = fmaf(x, log2e, cvt_magic);
    q -= cvt_magic;
    x = fmaf(q, neg_ln2hi, x);
    x = fmaf(q, neg_ln2lo, x);
    float x2 = x * x;
    float poly = fmaf(p0, x, p1);
    poly = fmaf(poly, x, p2);
    poly = fmaf(poly, x, p3);
    poly = fmaf(poly, x, p4);
    poly = fmaf(poly, x, p5);
    poly = fmaf(poly, x2, x);
    poly = poly + 1.0f;
    return ldexpf(poly, (int)q);
}

__device__ __forceinline__ float sigmoid_np(float x) {
    float e = np_expf(-x);
    return 1.0f / (1.0f + e);
}

// ---- xor-shuffle of a u64, cheapest HW path per distance (verified R4-R8) ----
// The extra VALU cost of the u64 key vs u32 is hidden under the gather wall
// (R6 measured: u32 sort was NOT faster), so keep the simpler verified u64 path.
template <int CTRL>
__device__ __forceinline__ unsigned long long xor_dpp_u64(unsigned long long v) {
    int lo = (int)(unsigned)v;
    int hi = (int)(v >> 32);
    lo = __builtin_amdgcn_update_dpp(lo, lo, CTRL, 0xF, 0xF, true);
    hi = __builtin_amdgcn_update_dpp(hi, hi, CTRL, 0xF, 0xF, true);
    return ((unsigned long long)(unsigned)hi << 32) | (unsigned)lo;
}

template <int OFF>
__device__ __forceinline__ unsigned long long xor_swz_u64(unsigned long long v) {
    int lo = (int)(unsigned)v;
    int hi = (int)(v >> 32);
    lo = __builtin_amdgcn_ds_swizzle(lo, OFF);
    hi = __builtin_amdgcn_ds_swizzle(hi, OFF);
    return ((unsigned long long)(unsigned)hi << 32) | (unsigned)lo;
}

template <int J>
__device__ __forceinline__ unsigned long long xorshfl_u64(unsigned long long v) {
    if constexpr (J == 1)       return xor_dpp_u64<0xB1>(v);    // quad_perm [1,0,3,2]
    else if constexpr (J == 2)  return xor_dpp_u64<0x4E>(v);    // quad_perm [2,3,0,1]
    else if constexpr (J == 4)  return xor_swz_u64<0x101F>(v);  // swizzle xor4
    else if constexpr (J == 8)  return xor_dpp_u64<0x128>(v);   // row_ror:8 == xor8
    else if constexpr (J == 16) return xor_swz_u64<0x401F>(v);  // swizzle xor16
    else {                                                      // J == 32
        int lo = (int)(unsigned)v;
        int hi = (int)(v >> 32);
        lo = __shfl_xor(lo, 32, 64);
        hi = __shfl_xor(hi, 32, 64);
        return ((unsigned long long)(unsigned)hi << 32) | (unsigned)lo;
    }
}

template <int K, int J>
__device__ __forceinline__ void stage(unsigned long long& key, int lane) {
    unsigned long long other = xorshfl_u64<J>(key);
    const bool dir = ((lane & J) == 0) == ((lane & K) == 0);
    key = ((key > other) != dir) ? other : key;
}

// Fused single kernel (R4 structure — fastest measured: 123 us dispatch,
// 270 us total). One wave per segment of D=64 edges. The kernel is bound by
// the divergent-gather service rate (~16.7M random 4B requests at ~57/cyc
// chip-wide); all VALU (inline sigmoid + u64 bitonic sort) hides under it.
__global__ __launch_bounds__(256)
void topk_kernel(const int* __restrict__ edge_index,   // [2, E]
                 const float* __restrict__ logits,
                 int* __restrict__ out,                // [2, nseg*K]
                 int E, int nseg, int outHalf) {
    const int tid = threadIdx.x;
    const int lane = tid & 63;
    const int w = (blockIdx.x << 2) | (tid >> 6);   // 4 waves/block
    if (w >= nseg) return;
    const int e = (w << 6) | lane;

    int src = edge_index[e];
    int dst = edge_index[E + e];

    float ss = sigmoid_np(logits[src]);             // the irreducible gather
    int dst0 = __builtin_amdgcn_readfirstlane(dst); // wave-uniform -> s_load
    float sd = sigmoid_np(logits[dst0]);
    float sim = 1.0f - fabsf(ss - sd);              // np f32 pipeline

    unsigned long long key =
        ((unsigned long long)__float_as_uint(sim) << 6) |
        (unsigned long long)(lane ^ 63);

    // Full 64-lane bitonic sort, descending; j=1,2,8 on DPP (VALU),
    // j=4,16 on ds_swizzle, j=32 on bpermute. Verified rounds 3-8.
    stage<2, 1>(key, lane);
    stage<4, 2>(key, lane);   stage<4, 1>(key, lane);
    stage<8, 4>(key, lane);   stage<8, 2>(key, lane);   stage<8, 1>(key, lane);
    stage<16, 8>(key, lane);  stage<16, 4>(key, lane);  stage<16, 2>(key, lane);
    stage<16, 1>(key, lane);
    stage<32, 16>(key, lane); stage<32, 8>(key, lane);  stage<32, 4>(key, lane);
    stage<32, 2>(key, lane);  stage<32, 1>(key, lane);
    stage<64, 32>(key, lane); stage<64, 16>(key, lane); stage<64, 8>(key, lane);
    stage<64, 4>(key, lane);  stage<64, 2>(key, lane);  stage<64, 1>(key, lane);

    // Lane r (r < K) holds rank-r key; pull the owning lane's src.
    int origLane = ((int)(key & 63)) ^ 63;
    int sel_src = __shfl(src, origLane, 64);

    if (lane < K_KEEP) {
        int base = (w << 5) | lane;
        out[base] = sel_src;           // row 0: selected src
        out[outHalf + base] = dst;     // row 1: dst (segment-constant)
    }
}

extern "C" void kernel_launch(void* const* d_in, const int* in_sizes, int n_in,
                              void* d_out, int out_size, void* d_ws, size_t ws_size,
                              hipStream_t stream) {
    const float* logits = (const float*)d_in[0];
    const int* edge_index = (const int*)d_in[1];
    int E = in_sizes[1] / 2;             // 2^24, fits int
    int nseg = E / D_EDGES;              // 2^18
    int outHalf = nseg * K_KEEP;         // 2^23
    int* out = (int*)d_out;

    int blocks = (nseg + 3) / 4;         // 4 waves (segments) per 256-thr block
    topk_kernel<<<blocks, 256, 0, stream>>>(edge_index, logits, out,
                                            E, nseg, outHalf);
}